// Round 1
// baseline (87206.097 us; speedup 1.0000x reference)
//
#include <hip/hip_runtime.h>
#include <hip/hip_bf16.h>
#include <math.h>

#define NODES 16384
#define D 512
#define H 512
#define G3 1536
#define GRU_WGS 32
#define GRU_SLICE 16   // H / GRU_WGS
#define GRU_THREADS 512

__device__ __forceinline__ float sigmoidf_(float x) {
    return 1.0f / (1.0f + __expf(-x));
}

// ---------------- degree / norm ----------------
__global__ void deg_init(float* deg, int N) {
    int i = blockIdx.x * blockDim.x + threadIdx.x;
    if (i < N) deg[i] = 2.0f;   // two self loops per node
}
__global__ void deg_count(const int* __restrict__ ei, float* deg, int E) {
    int e = blockIdx.x * blockDim.x + threadIdx.x;
    if (e < E) atomicAdd(&deg[ei[E + e]], 1.0f);   // col = targets
}
__global__ void deg_inv(const float* __restrict__ deg, float* dinv, int N) {
    int i = blockIdx.x * blockDim.x + threadIdx.x;
    if (i < N) dinv[i] = rsqrtf(deg[i]);           // deg >= 2 always
}

// ---------------- f32 tiled GEMM: C[M,N] = A[M,K] @ B (+bias) ----------------
// NT=false: B is [K,N] row-major.  NT=true: B is [N,K] row-major (C = A @ B^T).
template<bool NT, bool BIAS>
__global__ __launch_bounds__(256) void gemm64(
    const float* __restrict__ A, const float* __restrict__ B,
    const float* __restrict__ bias, float* __restrict__ C,
    int M, int N, int K)
{
    __shared__ float As[16][68];
    __shared__ float Bs[16][68];
    const int tid = threadIdx.x;
    const int tx = tid & 15, ty = tid >> 4;
    const int bm = blockIdx.y * 64, bn = blockIdx.x * 64;
    float acc[4][4] = {};
    for (int k0 = 0; k0 < K; k0 += 16) {
        #pragma unroll
        for (int l = 0; l < 4; ++l) {
            int idx = tid + l * 256;
            int m = idx >> 4, kk = idx & 15;
            As[kk][m] = A[(size_t)(bm + m) * K + (k0 + kk)];
            if (NT) {
                int n = idx >> 4, k2 = idx & 15;
                Bs[k2][n] = B[(size_t)(bn + n) * K + (k0 + k2)];
            } else {
                int k2 = idx >> 6, n = idx & 63;
                Bs[k2][n] = B[(size_t)(k0 + k2) * N + (bn + n)];
            }
        }
        __syncthreads();
        #pragma unroll
        for (int kk = 0; kk < 16; ++kk) {
            float4 av = *(const float4*)&As[kk][ty * 4];
            float4 bv = *(const float4*)&Bs[kk][tx * 4];
            float a[4] = {av.x, av.y, av.z, av.w};
            float b[4] = {bv.x, bv.y, bv.z, bv.w};
            #pragma unroll
            for (int i = 0; i < 4; ++i)
                #pragma unroll
                for (int j = 0; j < 4; ++j)
                    acc[i][j] = fmaf(a[i], b[j], acc[i][j]);
        }
        __syncthreads();
    }
    #pragma unroll
    for (int i = 0; i < 4; ++i)
        #pragma unroll
        for (int j = 0; j < 4; ++j) {
            float v = acc[i][j];
            if (BIAS) v += bias[bn + tx * 4 + j];
            C[(size_t)(bm + ty * 4 + i) * N + (bn + tx * 4 + j)] = v;
        }
}

// ---------------- GCN aggregation ----------------
// init: gcn[n,k] = bias[k] + 2*dinv[n]^2 * xw[n,k]   (the two self loops)
__global__ void gcn_init(const float* __restrict__ xw, const float* __restrict__ dinv,
                         const float* __restrict__ bias, float* __restrict__ gcn, int N) {
    int n = blockIdx.x;
    int k = threadIdx.x;           // 512 threads
    float di = dinv[n];
    gcn[(size_t)n * D + k] = bias[k] + 2.0f * di * di * xw[(size_t)n * D + k];
}
// scatter: gcn[col,:] += dinv[row]*dinv[col] * xw[row,:]
__global__ void scatter_edges(const int* __restrict__ ei, const float* __restrict__ xw,
                              const float* __restrict__ dinv, float* __restrict__ gcn, int E) {
    int e = blockIdx.x;
    int row = ei[e], col = ei[E + e];
    float norm = dinv[row] * dinv[col];
    int k = threadIdx.x;           // 512 threads
    atomicAdd(&gcn[(size_t)col * D + k], norm * xw[(size_t)row * D + k]);
}

// ---------------- GRU ----------------
__global__ void gru_init(const float* __restrict__ hidden, float* hbuf, int* flags) {
    int i = threadIdx.x;           // 512 threads
    hbuf[i] = hidden[i];
    hbuf[H + i] = 0.0f;
    if (i < GRU_WGS) flags[i] = 0;
}

// 32 persistent WGs x 512 threads. WG w owns h[16w .. 16w+16) and the 48
// corresponding rows of w_hh, held in registers (48 VGPR/thread).
// Per step: spin on flags -> load h -> 48 dot products (wave-split) ->
// gates -> write h slice + release flag.
__global__ __launch_bounds__(GRU_THREADS, 1) void gru_kernel(
    const float* __restrict__ gi, const float* __restrict__ w_hh,
    const float* __restrict__ b_hh, float* __restrict__ hbuf,
    int* flags, float* __restrict__ out, int T)
{
    const int wg = blockIdx.x;
    const int tid = threadIdx.x;
    const int wave = tid >> 6;
    const int lane = tid & 63;

    __shared__ float h_lds[H];
    __shared__ float dots[48];

    // local rows lr = wave*6 + r ; lr<16 -> r-gate, <32 -> z-gate, else n-gate
    float w_reg[6][8];
    float bhh[6];
    #pragma unroll
    for (int r = 0; r < 6; ++r) {
        int lr = wave * 6 + r;
        int grow;
        if (lr < 16)      grow = wg * GRU_SLICE + lr;
        else if (lr < 32) grow = H + wg * GRU_SLICE + (lr - 16);
        else              grow = 2 * H + wg * GRU_SLICE + (lr - 32);
        bhh[r] = b_hh[grow];
        #pragma unroll
        for (int m = 0; m < 8; ++m)
            w_reg[r][m] = w_hh[(size_t)grow * H + lane + 64 * m];
    }

    // gi prefetch registers (threads 0..15 hold the 3 gate inputs for elem j)
    float gir = 0.f, giz = 0.f, gin = 0.f;
    if (tid < GRU_SLICE) {
        size_t base = (size_t)wg * GRU_SLICE + tid;
        gir = gi[base]; giz = gi[base + H]; gin = gi[base + 2 * H];
    }

    for (int t = 0; t < T; ++t) {
        if (t > 0) {
            if (tid < GRU_WGS) {
                while (__hip_atomic_load(&flags[tid], __ATOMIC_RELAXED,
                                         __HIP_MEMORY_SCOPE_AGENT) < t) {
                    __builtin_amdgcn_s_sleep(1);
                }
            }
            __syncthreads();
            __builtin_amdgcn_fence(__ATOMIC_ACQUIRE, "agent");
        }
        h_lds[tid] = hbuf[(t & 1) * H + tid];
        __syncthreads();

        // prefetch next step's gi (latency hidden under compute+sync)
        float ngir = 0.f, ngiz = 0.f, ngin = 0.f;
        if (tid < GRU_SLICE && t + 1 < T) {
            size_t base = (size_t)(t + 1) * G3 + (size_t)wg * GRU_SLICE + tid;
            ngir = gi[base]; ngiz = gi[base + H]; ngin = gi[base + 2 * H];
        }

        float hr[8];
        #pragma unroll
        for (int m = 0; m < 8; ++m) hr[m] = h_lds[lane + 64 * m];

        #pragma unroll
        for (int r = 0; r < 6; ++r) {
            float s = 0.f;
            #pragma unroll
            for (int m = 0; m < 8; ++m) s = fmaf(w_reg[r][m], hr[m], s);
            #pragma unroll
            for (int off = 32; off > 0; off >>= 1)
                s += __shfl_xor(s, off, 64);
            if (lane == 0) dots[wave * 6 + r] = s + bhh[r];
        }
        __syncthreads();

        if (tid < GRU_SLICE) {
            int j = wg * GRU_SLICE + tid;
            float hold = h_lds[j];
            float rg = sigmoidf_(gir + dots[tid]);
            float zg = sigmoidf_(giz + dots[16 + tid]);
            float ng = tanhf(gin + rg * dots[32 + tid]);
            float hn = (1.f - zg) * ng + zg * hold;
            hbuf[((t + 1) & 1) * H + j] = hn;
            out[(size_t)t * H + j] = hn;
            if (t == T - 1) out[(size_t)T * H + j] = hn;   // h_last tail
        }
        __syncthreads();   // h-slice stores complete (barrier drains vmcnt)
        if (tid == 0)
            __hip_atomic_store(&flags[wg], t + 1, __ATOMIC_RELEASE,
                               __HIP_MEMORY_SCOPE_AGENT);
        gir = ngir; giz = ngiz; gin = ngin;
    }
}

// ---------------- launcher ----------------
extern "C" void kernel_launch(void* const* d_in, const int* in_sizes, int n_in,
                              void* d_out, int out_size, void* d_ws, size_t ws_size,
                              hipStream_t stream) {
    const float* x      = (const float*)d_in[0];  // [N, D]
    const int*   ei     = (const int*)d_in[1];    // [2, E]
    const float* hidden = (const float*)d_in[2];  // [1, H]
    const float* gw     = (const float*)d_in[3];  // [D, H]
    const float* gb     = (const float*)d_in[4];  // [H]
    const float* w_ih   = (const float*)d_in[5];  // [3H, H]
    const float* w_hh   = (const float*)d_in[6];  // [3H, H]
    const float* b_ih   = (const float*)d_in[7];  // [3H]
    const float* b_hh   = (const float*)d_in[8];  // [3H]
    float* out = (float*)d_out;

    const int N = in_sizes[0] / D;   // 16384
    const int E = in_sizes[1] / 2;   // 262144

    // ws layout (floats): deg[16384] dinv[16384] hbuf[1024] flags | gcn[N*D] | gi[N*3H]
    float* ws   = (float*)d_ws;
    float* deg  = ws;
    float* dinv = ws + 16384;
    float* hbuf = ws + 32768;
    int*   flags = (int*)(ws + 33792);
    float* gcn  = ws + 65536;
    float* gi   = gcn + (size_t)N * D;
    float* xw   = gi;   // alias: xw dies before gi is written

    // 1) degrees + normalization
    deg_init<<<(N + 255) / 256, 256, 0, stream>>>(deg, N);
    deg_count<<<(E + 255) / 256, 256, 0, stream>>>(ei, deg, E);
    deg_inv<<<(N + 255) / 256, 256, 0, stream>>>(deg, dinv, N);

    // 2) xw = x @ gcn_weight   [N, H]
    gemm64<false, false><<<dim3(H / 64, N / 64), 256, 0, stream>>>(
        x, gw, nullptr, xw, N, H, D);

    // 3) GCN aggregation -> gcn
    gcn_init<<<N, 512, 0, stream>>>(xw, dinv, gb, gcn, N);
    scatter_edges<<<E, 512, 0, stream>>>(ei, xw, dinv, gcn, E);

    // 4) gi = gcn @ w_ih^T + b_ih   [N, 3H]  (overwrites xw region)
    gemm64<true, true><<<dim3(G3 / 64, N / 64), 256, 0, stream>>>(
        gcn, w_ih, b_ih, gi, N, G3, H);

    // 5) GRU recurrence (persistent, 32 WGs, custom device-scope sync)
    gru_init<<<1, 512, 0, stream>>>(hidden, hbuf, flags);
    gru_kernel<<<GRU_WGS, GRU_THREADS, 0, stream>>>(
        gi, w_hh, b_hh, hbuf, flags, out, N);
}